// Round 12
// baseline (434.298 us; speedup 1.0000x reference)
//
#include <hip/hip_runtime.h>
#include <hip/hip_fp16.h>
#include <math.h>

#define NCH 32
#define CHV (64*32*64)      // one channel volume
#define NB 4
#define NT2 512             // tile-slots per n: 32zt * 8yt * 2chh
#define INVC (1.0f/(32.0f+1e-6f))
#define D2R 0.017453292519943295f
#define R2D 57.29577951308232f

// ---------------------------------------------------------------------------
// Kernel 1: fused rotate-warp(feat1) x 27-offset correlation vs feat0.
// Block = (b, chh, 2z x 4y x 64x tile): 192 threads = 3 independent waves,
// one per rotation (wave 1 = identity). NO LDS / barriers. Channel loop is
// software-pipelined 2-deep (T14): channel ch+1's 32 feat1 gathers are issued
// into a register buffer BEFORE channel ch's compute, so their L1/L2 latency
// hides under ~600 cycles of FMA work. feat0 rows demand-loaded (coalesced).
// Register diet: bilinear weights packed __half2, aHi folded into aLo hop-bit.
// ---------------------------------------------------------------------------
__global__ __launch_bounds__(192) void k_heat(const float* __restrict__ feat0,
                                              const float* __restrict__ feat1,
                                              float* __restrict__ partial)
{
    // XCD-chunked remap: XCD x gets 256 consecutive nids = exactly one (b,chh)
    const int lid = (int)blockIdx.x;            // 0..2047
    const int nid = (lid & 7) * 256 + (lid >> 3);
    const int yt  = nid & 7;
    const int zt  = (nid >> 3) & 31;
    const int chh = (nid >> 8) & 1;
    const int b   = nid >> 9;

    const int tid = (int)threadIdx.x;
    const int wv = tid >> 6;           // rotation 0,1,2 (1 = identity)
    const int lane = tid & 63;
    const int tx = lane & 15, ty = lane >> 4;
    const int x0 = 4 * tx;
    const int y  = 4 * yt + ty;
    const int z0 = 2 * zt;             // thread owns z0, z0+1
    const bool yedge = (yt == 0) || (yt == 7);
    const bool ident = (wv == 1);

    const float* f0base = feat0 + ((size_t)b * NCH + chh * 16) * CHV;
    const float* f1base = feat1 + ((size_t)b * NCH + chh * 16) * CHV;

    // ---- bilinear gather setup (channel-invariant); packed to save VGPRs ----
    // aPk = aLo | (hop<<20); aHi = aLo + hop*2048. Weights as __half2 pairs.
    int aPk[2][4];
    __half2 wxp[2][4], wzp[2][4];
    if (!ident) {
        const float th = 4.0f * (float)(wv - 1) * D2R;
        const float cs = cosf(th), sn = sinf(th);
        #pragma unroll
        for (int k = 0; k < 2; ++k) {
            #pragma unroll
            for (int i = 0; i < 4; ++i) {
                const float rx = (float)(x0 + i) - 31.5f;
                const float rz = (float)(z0 + k) - 31.5f;
                const float sx = cs * rx - sn * rz + 31.5f;
                const float sz = sn * rx + cs * rz + 31.5f;
                const float xf = floorf(sx), zf = floorf(sz);
                const float fx = sx - xf, fz = sz - zf;
                const int ix = (int)xf, iz = (int)zf;
                const float W0 = ((unsigned)ix < 64u) ? (1.0f - fx) : 0.0f;
                const float W1 = ((unsigned)(ix + 1) < 64u) ? fx : 0.0f;
                // bx in [0,62]; sample = A_*f[bx] + B_*f[bx+1] covers all cases
                int bx; float A_, B_;
                if (ix < 0)       { bx = 0;  A_ = W1;   B_ = 0.0f; }
                else if (ix > 62) { bx = 62; A_ = 0.0f; B_ = W0;  }
                else              { bx = ix; A_ = W0;   B_ = W1;  }
                wxp[k][i] = __floats2half2_rn(A_, B_);
                const float za = ((unsigned)iz < 64u) ? (1.0f - fz) : 0.0f;
                const float zb = ((unsigned)(iz + 1) < 64u) ? fz : 0.0f;
                wzp[k][i] = __floats2half2_rn(za, zb);
                const int aLo = min(max(iz, 0), 63) * 2048 + y * 64 + bx;
                const int hop = (iz >= 0 && iz <= 62) ? 1 : 0;
                aPk[k][i] = aLo | (hop << 20);
            }
        }
    }
    const int iA = z0 * 2048 + y * 64 + x0;   // identity rows (z0; z0+1 = +2048)

    // y-row masks + clamped offsets incl. x0 (channel-invariant, per lane)
    float myv[3]; int yoffc[3];
    #pragma unroll
    for (int yri = 0; yri < 3; ++yri) {
        const int yy = y - 1 + yri;
        myv[yri] = ((unsigned)yy < 32u) ? 1.0f : 0.0f;
        yoffc[yri] = min(max(yy, 0), 31) * 64 + x0;
    }

    float acc[27];
    #pragma unroll
    for (int o = 0; o < 27; ++o) acc[o] = 0.0f;

// ---- pipeline stage 1: issue channel CH's 32 gathers into buffer G ----
#define LOADG(G, CH)                                                            \
    {                                                                           \
        const float* f1c_ = f1base + (size_t)(CH) * CHV;                        \
        if (ident) {                                                            \
            const float4 v0_ = *(const float4*)(f1c_ + iA);                     \
            const float4 v1_ = *(const float4*)(f1c_ + iA + 2048);              \
            G[0] = v0_.x; G[1] = v0_.y; G[2] = v0_.z; G[3] = v0_.w;             \
            G[4] = v1_.x; G[5] = v1_.y; G[6] = v1_.z; G[7] = v1_.w;             \
        } else {                                                                \
            _Pragma("unroll")                                                   \
            for (int k_ = 0; k_ < 2; ++k_) {                                    \
                _Pragma("unroll")                                               \
                for (int i_ = 0; i_ < 4; ++i_) {                                \
                    const int ap_ = aPk[k_][i_];                                \
                    const int lo_ = ap_ & 0xFFFFF;                              \
                    const int hi_ = lo_ + ((ap_ >> 20) << 11);                  \
                    const int q_ = (k_ * 4 + i_) * 4;                           \
                    G[q_ + 0] = f1c_[lo_];     G[q_ + 1] = f1c_[lo_ + 1];       \
                    G[q_ + 2] = f1c_[hi_];     G[q_ + 3] = f1c_[hi_ + 1];       \
                }                                                               \
            }                                                                   \
        }                                                                       \
    }

#define ROWFMA(KK, OZP1, YRI)                                                   \
        { const int base_ = (OZP1) * 9 + (2 - (YRI)) * 3;                       \
          acc[base_ + 0] += g0[KK]*R.x + fr[KK][0]*R.y + fr[KK][1]*R.z + fr[KK][2]*R.w; \
          acc[base_ + 1] += fr[KK][0]*R.x + fr[KK][1]*R.y + fr[KK][2]*R.z + fr[KK][3]*R.w; \
          acc[base_ + 2] += fr[KK][1]*R.x + fr[KK][2]*R.y + fr[KK][3]*R.z + g5[KK]*R.w; }
#define CORRLOOP(MASKED)                                                        \
        _Pragma("unroll")                                                       \
        for (int zri = 0; zri < 4; ++zri) {                                     \
            const int zz = 2 * zt - 1 + zri;                                    \
            if (zz >= 0 && zz <= 63) {                                          \
                const float* rp = f0c_ + zz * 2048;                             \
                _Pragma("unroll")                                               \
                for (int yri = 0; yri < 3; ++yri) {                             \
                    float4 R = *(const float4*)(rp + yoffc[yri]);               \
                    if (MASKED) { const float m_ = myv[yri];                    \
                        R.x *= m_; R.y *= m_; R.z *= m_; R.w *= m_; }           \
                    if (zri == 0) { ROWFMA(0, 2, yri) }                         \
                    if (zri == 1) { ROWFMA(0, 1, yri) ROWFMA(1, 2, yri) }       \
                    if (zri == 2) { ROWFMA(0, 0, yri) ROWFMA(1, 1, yri) }       \
                    if (zri == 3) { ROWFMA(1, 0, yri) }                         \
                }                                                               \
            }                                                                   \
        }

// ---- pipeline stage 2: consume buffer G (loaded >= one compute ago) ----
#define COMPUTE(G, CH)                                                          \
    {                                                                           \
        const float* f0c_ = f0base + (size_t)(CH) * CHV;                        \
        float fr[2][4];                                                         \
        if (ident) {                                                            \
            _Pragma("unroll")                                                   \
            for (int i_ = 0; i_ < 4; ++i_) {                                    \
                fr[0][i_] = G[i_]; fr[1][i_] = G[4 + i_];                       \
            }                                                                   \
        } else {                                                                \
            _Pragma("unroll")                                                   \
            for (int k_ = 0; k_ < 2; ++k_) {                                    \
                _Pragma("unroll")                                               \
                for (int i_ = 0; i_ < 4; ++i_) {                                \
                    const int q_ = (k_ * 4 + i_) * 4;                           \
                    const float2 wx2 = __half22float2(wxp[k_][i_]);             \
                    const float2 wz2 = __half22float2(wzp[k_][i_]);             \
                    const float sLo = wx2.x * G[q_ + 0] + wx2.y * G[q_ + 1];    \
                    const float sHi = wx2.x * G[q_ + 2] + wx2.y * G[q_ + 3];    \
                    fr[k_][i_] = wz2.x * sLo + wz2.y * sHi;                     \
                }                                                               \
            }                                                                   \
        }                                                                       \
        float g0[2], g5[2];                                                     \
        _Pragma("unroll")                                                       \
        for (int k_ = 0; k_ < 2; ++k_) {                                        \
            const float a_ = __shfl_up(fr[k_][3], 1, 64);                       \
            const float c_ = __shfl_down(fr[k_][0], 1, 64);                     \
            g0[k_] = (tx == 0) ? 0.0f : a_;                                     \
            g5[k_] = (tx == 15) ? 0.0f : c_;                                    \
        }                                                                       \
        if (yedge) { CORRLOOP(1) } else { CORRLOOP(0) }                         \
    }

    float ga[32], gb[32];
    LOADG(ga, 0)
    #pragma unroll 1
    for (int ch = 0; ch < 16; ch += 2) {
        LOADG(gb, ch + 1)       // issue ch+1's gathers before computing ch
        COMPUTE(ga, ch)
        if (ch + 2 < 16) LOADG(ga, ch + 2)
        COMPUTE(gb, ch + 1)
    }
#undef COMPUTE
#undef CORRLOOP
#undef ROWFMA
#undef LOADG

    // ---- per-wave reduction (fixed order -> deterministic), direct write ----
    const int slot = (zt * 8 + yt) * 2 + chh;
    #pragma unroll 1
    for (int o = 0; o < 27; ++o) {
        float v = acc[o];
        #pragma unroll
        for (int d = 32; d >= 1; d >>= 1) v += __shfl_down(v, d, 64);
        if (lane == 0)
            partial[((size_t)((b * 3 + wv) * 27) + o) * NT2 + slot] = v;
    }
}

// ---------------------------------------------------------------------------
// Kernel 2: reduce partials (transposed layout: [n*27][512] rows, vectorized)
// -> heat, per-batch MLP, loss + matrices + params.
// ---------------------------------------------------------------------------
__global__ __launch_bounds__(256) void k_mlp(const float* __restrict__ partial,
                                             const float* __restrict__ camg,
                                             const float* __restrict__ W1,
                                             const float* __restrict__ b1,
                                             const float* __restrict__ W2,
                                             const float* __restrict__ b2,
                                             const float* __restrict__ W3,
                                             const float* __restrict__ b3,
                                             float* __restrict__ out,
                                             float* __restrict__ params)
{
    __shared__ float heat[324];
    __shared__ float f[81];
    __shared__ float h1[128];
    __shared__ float h2[128];
    __shared__ float denom_s;
    __shared__ float res[NB][8];
    const int tid = (int)threadIdx.x;

    for (int r = tid; r < 324; r += 256) {
        const float4* p = (const float4*)(partial + (size_t)r * NT2);
        float s0 = 0.0f, s1 = 0.0f, s2 = 0.0f, s3 = 0.0f;
        #pragma unroll 4
        for (int i = 0; i < NT2 / 4; ++i) {
            const float4 v = p[i];
            s0 += v.x; s1 += v.y; s2 += v.z; s3 += v.w;
        }
        heat[r] = ((s0 + s1) + (s2 + s3)) * INVC;
    }
    __syncthreads();

    for (int b = 0; b < NB; ++b) {
        if (tid < 81) {
            float v = heat[b * 81 + tid];
            f[tid] = (v >= 0.0f) ? v : 0.1f * v;
        }
        __syncthreads();
        if (tid == 0) {
            float ss = 0.0f;
            for (int k = 0; k < 81; ++k) ss += f[k] * f[k];
            denom_s = 1e-6f + sqrtf(ss);
        }
        __syncthreads();
        if (tid < 81) f[tid] = f[tid] / denom_s;
        __syncthreads();
        if (tid < 128) {
            float a = b1[tid];
            const float* wr = W1 + tid * 81;
            for (int k = 0; k < 81; ++k) a += wr[k] * f[k];
            h1[tid] = (a >= 0.0f) ? a : 0.1f * a;
        }
        __syncthreads();
        if (tid < 128) {
            float a = b2[tid];
            const float* wr = W2 + tid * 128;
            for (int k = 0; k < 128; ++k) a += wr[k] * h1[k];
            h2[tid] = (a >= 0.0f) ? a : 0.1f * a;
        }
        __syncthreads();
        if (tid < 4) {
            float a = b3[tid];
            const float* wr = W3 + tid * 128;
            for (int k = 0; k < 128; ++k) a += wr[k] * h2[k];
            res[b][4 + tid] = a;
        }
        __syncthreads();
        if (tid == 0) {
            const float r_out = res[b][4], yv = res[b][5], xv = res[b][6], zv = res[b][7];
            const float t2 = r_out * D2R;
            const float c2 = cosf(t2), s2 = sinf(t2);
            float* m = out + 1 + b * 16;
            m[0] = c2;  m[1] = 0.0f; m[2] = s2;  m[3] = -xv;
            m[4] = 0.0f; m[5] = 1.0f; m[6] = 0.0f; m[7] = -yv;
            m[8] = -s2; m[9] = 0.0f; m[10] = c2; m[11] = -zv;
            m[12] = 0.0f; m[13] = 0.0f; m[14] = 0.0f; m[15] = 1.0f;
            params[b * 8 + 0] = c2;
            params[b * 8 + 1] = s2;
            params[b * 8 + 2] = c2 * xv - s2 * zv;
            params[b * 8 + 3] = yv;
            params[b * 8 + 4] = s2 * xv + c2 * zv;
            res[b][0] = -xv; res[b][1] = -yv; res[b][2] = -zv;
            res[b][3] = atan2f(s2, c2) * R2D;
        }
        __syncthreads();
    }

    if (tid == 0) {
        float tl2 = 0.0f, dl2 = 0.0f;
        for (int b = 0; b < NB; ++b) {
            const float* g = camg + b * 16;
            const float dx = res[b][0] - g[3];
            const float dy = res[b][1] - g[7];
            const float dz = res[b][2] - g[11];
            tl2 += dx * dx + dy * dy + dz * dz;
            const float dg = atan2f(g[2], g[10]) * R2D;
            const float dd = res[b][3] - dg;
            dl2 += dd * dd;
        }
        out[0] = tl2 * 0.25f + dl2 * 0.25f;
    }
}

// ---------------------------------------------------------------------------
// Kernel 3: warp feat1 by estimated transform -> feat1_warped (d_out + 65).
// ---------------------------------------------------------------------------
__global__ __launch_bounds__(256) void k_warp(const float* __restrict__ feat1,
                                              const float* __restrict__ params,
                                              float* __restrict__ outw)
{
    const int b = blockIdx.y;
    const int p = (int)blockIdx.x * 256 + (int)threadIdx.x;
    const int z = p >> 11;
    const int y = (p >> 6) & 31;
    const int x = p & 63;

    const float cs = params[b * 8 + 0], sn = params[b * 8 + 1];
    const float tpx = params[b * 8 + 2], tpy = params[b * 8 + 3], tpz = params[b * 8 + 4];

    const float rx = (float)x - 31.5f;
    const float ry = (float)y - 15.5f;
    const float rz = (float)z - 31.5f;
    const float sx = cs * rx - sn * rz + tpx + 31.5f;
    const float sy = ry + tpy + 15.5f;
    const float sz = sn * rx + cs * rz + tpz + 31.5f;

    const float xf = floorf(sx), yf = floorf(sy), zf = floorf(sz);
    const float fx = sx - xf, fy = sy - yf, fz = sz - zf;
    const int ix = (int)xf, iy = (int)yf, iz = (int)zf;

    const float wx[2] = {1.0f - fx, fx};
    const float wy[2] = {1.0f - fy, fy};
    const float wz[2] = {1.0f - fz, fz};
    const int xs[2] = {min(max(ix, 0), 63), min(max(ix + 1, 0), 63)};
    const int ys[2] = {min(max(iy, 0), 31), min(max(iy + 1, 0), 31)};
    const int zs[2] = {min(max(iz, 0), 63), min(max(iz + 1, 0), 63)};
    const bool vx[2] = {(unsigned)ix < 64u, (unsigned)(ix + 1) < 64u};
    const bool vy[2] = {(unsigned)iy < 32u, (unsigned)(iy + 1) < 32u};
    const bool vz[2] = {(unsigned)iz < 64u, (unsigned)(iz + 1) < 64u};

    int idx[8]; float w[8];
    int q = 0;
    #pragma unroll
    for (int dz = 0; dz < 2; ++dz)
        #pragma unroll
        for (int dy = 0; dy < 2; ++dy)
            #pragma unroll
            for (int dx = 0; dx < 2; ++dx) {
                idx[q] = zs[dz] * 2048 + ys[dy] * 64 + xs[dx];
                w[q] = (vx[dx] && vy[dy] && vz[dz]) ? wx[dx] * wy[dy] * wz[dz] : 0.0f;
                ++q;
            }

    const float* f1b = feat1 + (size_t)b * NCH * CHV;
    float* ob = outw + (size_t)b * NCH * CHV;
    #pragma unroll 1
    for (int c = 0; c < NCH; ++c) {
        const float* f1c = f1b + (size_t)c * CHV;
        float a = 0.0f;
        #pragma unroll
        for (int k = 0; k < 8; ++k) a += w[k] * f1c[idx[k]];
        ob[(size_t)c * CHV + p] = a;
    }
}

// ---------------------------------------------------------------------------
extern "C" void kernel_launch(void* const* d_in, const int* in_sizes, int n_in,
                              void* d_out, int out_size, void* d_ws, size_t ws_size,
                              hipStream_t stream)
{
    (void)in_sizes; (void)n_in; (void)out_size; (void)ws_size;
    const float* feat0 = (const float*)d_in[0];
    const float* feat1 = (const float*)d_in[1];
    const float* camg  = (const float*)d_in[2];
    const float* W1 = (const float*)d_in[3];
    const float* b1 = (const float*)d_in[4];
    const float* W2 = (const float*)d_in[5];
    const float* b2 = (const float*)d_in[6];
    const float* W3 = (const float*)d_in[7];
    const float* b3 = (const float*)d_in[8];
    float* out = (float*)d_out;

    float* partial = (float*)d_ws;                 // 324*512 floats ~ 663 KB
    float* params  = partial + 324 * NT2;          // 32 floats

    hipLaunchKernelGGL(k_heat, dim3(2048), dim3(192), 0, stream,
                       feat0, feat1, partial);
    hipLaunchKernelGGL(k_mlp, dim3(1), dim3(256), 0, stream,
                       partial, camg, W1, b1, W2, b2, W3, b3, out, params);
    dim3 g3((64*32*64) / 256, NB);
    hipLaunchKernelGGL(k_warp, g3, dim3(256), 0, stream, feat1, params, out + 65);
}

// Round 13
// 233.071 us; speedup vs baseline: 1.8634x; 1.8634x over previous
//
#include <hip/hip_runtime.h>
#include <math.h>

typedef float v2f __attribute__((ext_vector_type(2)));

#define NCH 32
#define CHV (64*32*64)      // one channel volume
#define NB 4
#define NT2 512             // tile-slots per n: 32zt * 8yt * 2chh
#define INVC (1.0f/(32.0f+1e-6f))
#define D2R 0.017453292519943295f
#define R2D 57.29577951308232f

// feat1 LDS slab: 32 rows (8z x 4y) x pitch 72 (cols 0..63 data, 64..71 pad).
// 72 mod 32 = 8 -> bilinear scalar reads ~2-way; row*72*4B % 16 == 0 -> b128
// writes/reads aligned and conflict-free. OOB z rows staged as zeros.
#define P1 72
#define BUFSZ (32*P1)       // 2304 floats (9.2 KB) per buffer

// ---------------------------------------------------------------------------
// Kernel 1: fused rotate-warp(feat1) x 27-offset correlation vs feat0.
// Block = (b, chh, 2z x 4y x 64x tile): 256 threads.
// Waves 0/1/2 = rotations (-4deg / identity / +4deg); wave 3 = dedicated
// feat1 stager (double-buffered, 1 barrier/channel). Stager chunk map is
// fully compile-time (zr=k, yr=lane>>4, c=lane&15) -> zero register ballast;
// z-validity is a wave-uniform scalar branch. feat0 rows read direct from
// global (coalesced float4, L1/L2-resident, XCD-pinned working set).
// Correlation uses packed fp32 (v_pk_fma_f32 via float2 ext-vectors): 6
// instructions per 12-MAC row instead of 12.
// ---------------------------------------------------------------------------
__global__ __launch_bounds__(256) void k_heat(const float* __restrict__ feat0,
                                              const float* __restrict__ feat1,
                                              float* __restrict__ partial)
{
    __shared__ float L[2][BUFSZ];

    // XCD-chunked remap: XCD x gets 256 consecutive nids = exactly one (b,chh)
    const int lid = (int)blockIdx.x;            // 0..2047
    const int nid = (lid & 7) * 256 + (lid >> 3);
    const int yt  = nid & 7;
    const int zt  = (nid >> 3) & 31;
    const int chh = (nid >> 8) & 1;
    const int b   = nid >> 9;

    const int tid = (int)threadIdx.x;
    const int wv = tid >> 6;           // 0,1,2 compute rotations; 3 stager
    const int lane = tid & 63;
    const int tx = lane & 15, ty = lane >> 4;
    const int x0 = 4 * tx;
    const int y  = 4 * yt + ty;
    const int z0 = 2 * zt;             // thread owns z0, z0+1
    const bool yedge = (yt == 0) || (yt == 7);
    const bool ident = (wv == 1);

    const float* f0base = feat0 + ((size_t)b * NCH + chh * 16) * CHV;
    const float* f1base = feat1 + ((size_t)b * NCH + chh * 16) * CHV;

    // ---- bilinear setup (channel-invariant), rot waves 0/2 only ----
    // sample = wA*f[bx] + wB*f[bx+1] with bx in [0,62] (edge-rederived
    // weights); z corners: row zl (weight wZ) and zl+1 (weight 1-wZ), OOB
    // rows are zeros in LDS so no z masking needed.
    int aB[2][4];
    float wAx[2][4], wBx[2][4], wZl[2][4];
    if (!ident && wv < 3) {
        const float th = 4.0f * (float)(wv - 1) * D2R;
        const float cs = cosf(th), sn = sinf(th);
        #pragma unroll
        for (int k = 0; k < 2; ++k) {
            #pragma unroll
            for (int i = 0; i < 4; ++i) {
                const float rx = (float)(x0 + i) - 31.5f;
                const float rz = (float)(z0 + k) - 31.5f;
                const float sx = cs * rx - sn * rz + 31.5f;
                const float sz = sn * rx + cs * rz + 31.5f;
                const float xf = floorf(sx), zf = floorf(sz);
                const float fx = sx - xf, fz = sz - zf;
                const int ix = (int)xf, iz = (int)zf;
                int bx; float A_, B_;
                if (ix == -1)      { bx = 0;  A_ = fx;        B_ = 0.0f; }
                else if (ix == 63) { bx = 62; A_ = 0.0f;      B_ = 1.0f - fx; }
                else if ((unsigned)ix <= 62u) { bx = ix; A_ = 1.0f - fx; B_ = fx; }
                else               { bx = 0;  A_ = 0.0f;      B_ = 0.0f; }
                wAx[k][i] = A_; wBx[k][i] = B_;
                wZl[k][i] = 1.0f - fz;
                const int zl = min(max(iz - (2 * zt - 3), 0), 6);
                aB[k][i] = (zl * 4 + ty) * P1 + bx;
            }
        }
    }
    const int iA0 = (12 + ty) * P1 + x0;      // identity z0 row (zr=3)
    const int iA1 = iA0 + 4 * P1;             // identity z0+1 row (zr=4)

    // y-row masks + clamped offsets incl. x0 (channel-invariant, per lane)
    float myv[3]; int yoffc[3];
    #pragma unroll
    for (int yri = 0; yri < 3; ++yri) {
        const int yy = y - 1 + yri;
        myv[yri] = ((unsigned)yy < 32u) ? 1.0f : 0.0f;
        yoffc[yri] = min(max(yy, 0), 31) * 64 + x0;
    }

    // Packed accumulators: accP[r9] = {acc[3r9+0], acc[3r9+1]};
    // accS[r9] horizontally-summed at epilogue gives acc[3r9+2].
    v2f accP[9], accS[9];
    #pragma unroll
    for (int r = 0; r < 9; ++r) { accP[r] = (v2f){0.f, 0.f}; accS[r] = (v2f){0.f, 0.f}; }

// ---- stager: compile-time chunk map, wave-uniform z-validity branch ----
#define STAGE_CH(CHN, LDST)                                                     \
    {                                                                           \
        const float* f1c_ = f1base + (size_t)(CHN) * CHV;                       \
        float* Ln_ = (LDST);                                                    \
        const int yr_ = lane >> 4, c4_ = (lane & 15) << 2;                      \
        const int wb_ = yr_ * P1 + c4_;                                         \
        const int sb_ = (4 * yt + yr_) * 64 + c4_;                              \
        _Pragma("unroll")                                                       \
        for (int k_ = 0; k_ < 8; ++k_) {                                        \
            const int zs_ = 2 * zt - 3 + k_;                                    \
            float4 v_ = {0.0f, 0.0f, 0.0f, 0.0f};                               \
            if (zs_ >= 0 && zs_ < 64)                                           \
                v_ = *(const float4*)(f1c_ + zs_ * 2048 + sb_);                 \
            *(float4*)&Ln_[k_ * (4 * P1) + wb_] = v_;                           \
        }                                                                       \
    }

    // prologue: stager fills channel 0 into buffer 0
    if (wv == 3) STAGE_CH(0, &L[0][0])
    __syncthreads();

#define PKFMA(ACC, AB, S) { v2f rb_ = {(S), (S)}; ACC = ACC + (AB) * rb_; }
#define ROWFMA(KK, OZP1, YRI)                                                   \
        { const int r9_ = (OZP1) * 3 + (2 - (YRI));                             \
          PKFMA(accP[r9_], fA0##KK, R.x)                                        \
          PKFMA(accP[r9_], fB0##KK, R.y)                                        \
          PKFMA(accP[r9_], fA1##KK, R.z)                                        \
          PKFMA(accP[r9_], fB1##KK, R.w)                                        \
          { v2f rxy_ = {R.x, R.y}, rzw_ = {R.z, R.w};                           \
            accS[r9_] = accS[r9_] + fA1##KK * rxy_ + fB2##KK * rzw_; } }
#define CORRLOOP(MASKED)                                                        \
        _Pragma("unroll")                                                       \
        for (int zri = 0; zri < 4; ++zri) {                                     \
            const int zz = 2 * zt - 1 + zri;                                    \
            if (zz >= 0 && zz <= 63) {                                          \
                const float* rp = f0c + zz * 2048;                              \
                _Pragma("unroll")                                               \
                for (int yri = 0; yri < 3; ++yri) {                             \
                    float4 R = *(const float4*)(rp + yoffc[yri]);               \
                    if (MASKED) { const float m_ = myv[yri];                    \
                        R.x *= m_; R.y *= m_; R.z *= m_; R.w *= m_; }           \
                    if (zri == 0) { ROWFMA(0, 2, yri) }                         \
                    if (zri == 1) { ROWFMA(0, 1, yri) ROWFMA(1, 2, yri) }       \
                    if (zri == 2) { ROWFMA(0, 0, yri) ROWFMA(1, 1, yri) }       \
                    if (zri == 3) { ROWFMA(1, 0, yri) }                         \
                }                                                               \
            }                                                                   \
        }

    #pragma unroll 1
    for (int ch = 0; ch < 16; ++ch) {
        if (wv == 3) {
            if (ch + 1 < 16) STAGE_CH(ch + 1, &L[(ch + 1) & 1][0])
        } else {
            const float* Lb = &L[ch & 1][0];

            // ---- featN sample: fr[k][i] for owned voxels ----
            float fr[2][4];
            if (ident) {
                const float4 v0 = *(const float4*)&Lb[iA0];
                const float4 v1 = *(const float4*)&Lb[iA1];
                fr[0][0] = v0.x; fr[0][1] = v0.y; fr[0][2] = v0.z; fr[0][3] = v0.w;
                fr[1][0] = v1.x; fr[1][1] = v1.y; fr[1][2] = v1.z; fr[1][3] = v1.w;
            } else {
                #pragma unroll
                for (int k = 0; k < 2; ++k) {
                    #pragma unroll
                    for (int i = 0; i < 4; ++i) {
                        const int a = aB[k][i];
                        const float p00 = Lb[a], p01 = Lb[a + 1];
                        const float p10 = Lb[a + 4 * P1], p11 = Lb[a + 4 * P1 + 1];
                        const float sLo = wAx[k][i] * p00 + wBx[k][i] * p01;
                        const float sHi = wAx[k][i] * p10 + wBx[k][i] * p11;
                        fr[k][i] = sHi + wZl[k][i] * (sLo - sHi);
                    }
                }
            }

            // ---- featN x-extension (4 shuffles/ch) ----
            float g0[2], g5[2];
            #pragma unroll
            for (int k = 0; k < 2; ++k) {
                const float a = __shfl_up(fr[k][3], 1, 64);
                const float c = __shfl_down(fr[k][0], 1, 64);
                g0[k] = (tx == 0) ? 0.0f : a;
                g5[k] = (tx == 15) ? 0.0f : c;
            }

            // ---- packed operand pairs (per k) ----
            const v2f fA00 = {g0[0],    fr[0][0]}, fA01 = {g0[1],    fr[1][0]};
            const v2f fB00 = {fr[0][0], fr[0][1]}, fB01 = {fr[1][0], fr[1][1]};
            const v2f fA10 = {fr[0][1], fr[0][2]}, fA11 = {fr[1][1], fr[1][2]};
            const v2f fB10 = {fr[0][2], fr[0][3]}, fB11 = {fr[1][2], fr[1][3]};
            const v2f fB20 = {fr[0][3], g5[0]},    fB21 = {fr[1][3], g5[1]};

            // ---- correlation: 12 feat0 rows direct from global ----
            const float* f0c = f0base + (size_t)ch * CHV;
            __builtin_amdgcn_s_setprio(1);
            if (yedge) { CORRLOOP(1) } else { CORRLOOP(0) }
            __builtin_amdgcn_s_setprio(0);
        }
        __syncthreads();
    }
#undef CORRLOOP
#undef ROWFMA
#undef PKFMA
#undef STAGE_CH

    // ---- per-wave reduction (fixed order -> deterministic), direct write ----
    if (wv < 3) {
        const int slot = (zt * 8 + yt) * 2 + chh;
        #pragma unroll
        for (int r9 = 0; r9 < 9; ++r9) {
            float vals[3];
            vals[0] = accP[r9].x;
            vals[1] = accP[r9].y;
            vals[2] = accS[r9].x + accS[r9].y;
            #pragma unroll
            for (int rm = 0; rm < 3; ++rm) {
                float v = vals[rm];
                #pragma unroll
                for (int d = 32; d >= 1; d >>= 1) v += __shfl_down(v, d, 64);
                if (lane == 0)
                    partial[((size_t)((b * 3 + wv) * 27) + (r9 * 3 + rm)) * NT2 + slot] = v;
            }
        }
    }
}

// ---------------------------------------------------------------------------
// Kernel 2: reduce partials (transposed layout: [n*27][512] rows, vectorized)
// -> heat, per-batch MLP, loss + matrices + params.
// ---------------------------------------------------------------------------
__global__ __launch_bounds__(256) void k_mlp(const float* __restrict__ partial,
                                             const float* __restrict__ camg,
                                             const float* __restrict__ W1,
                                             const float* __restrict__ b1,
                                             const float* __restrict__ W2,
                                             const float* __restrict__ b2,
                                             const float* __restrict__ W3,
                                             const float* __restrict__ b3,
                                             float* __restrict__ out,
                                             float* __restrict__ params)
{
    __shared__ float heat[324];
    __shared__ float f[81];
    __shared__ float h1[128];
    __shared__ float h2[128];
    __shared__ float denom_s;
    __shared__ float res[NB][8];
    const int tid = (int)threadIdx.x;

    for (int r = tid; r < 324; r += 256) {
        const float4* p = (const float4*)(partial + (size_t)r * NT2);
        float s0 = 0.0f, s1 = 0.0f, s2 = 0.0f, s3 = 0.0f;
        #pragma unroll 4
        for (int i = 0; i < NT2 / 4; ++i) {
            const float4 v = p[i];
            s0 += v.x; s1 += v.y; s2 += v.z; s3 += v.w;
        }
        heat[r] = ((s0 + s1) + (s2 + s3)) * INVC;
    }
    __syncthreads();

    for (int b = 0; b < NB; ++b) {
        if (tid < 81) {
            float v = heat[b * 81 + tid];
            f[tid] = (v >= 0.0f) ? v : 0.1f * v;
        }
        __syncthreads();
        if (tid == 0) {
            float ss = 0.0f;
            for (int k = 0; k < 81; ++k) ss += f[k] * f[k];
            denom_s = 1e-6f + sqrtf(ss);
        }
        __syncthreads();
        if (tid < 81) f[tid] = f[tid] / denom_s;
        __syncthreads();
        if (tid < 128) {
            float a = b1[tid];
            const float* wr = W1 + tid * 81;
            for (int k = 0; k < 81; ++k) a += wr[k] * f[k];
            h1[tid] = (a >= 0.0f) ? a : 0.1f * a;
        }
        __syncthreads();
        if (tid < 128) {
            float a = b2[tid];
            const float* wr = W2 + tid * 128;
            for (int k = 0; k < 128; ++k) a += wr[k] * h1[k];
            h2[tid] = (a >= 0.0f) ? a : 0.1f * a;
        }
        __syncthreads();
        if (tid < 4) {
            float a = b3[tid];
            const float* wr = W3 + tid * 128;
            for (int k = 0; k < 128; ++k) a += wr[k] * h2[k];
            res[b][4 + tid] = a;
        }
        __syncthreads();
        if (tid == 0) {
            const float r_out = res[b][4], yv = res[b][5], xv = res[b][6], zv = res[b][7];
            const float t2 = r_out * D2R;
            const float c2 = cosf(t2), s2 = sinf(t2);
            float* m = out + 1 + b * 16;
            m[0] = c2;  m[1] = 0.0f; m[2] = s2;  m[3] = -xv;
            m[4] = 0.0f; m[5] = 1.0f; m[6] = 0.0f; m[7] = -yv;
            m[8] = -s2; m[9] = 0.0f; m[10] = c2; m[11] = -zv;
            m[12] = 0.0f; m[13] = 0.0f; m[14] = 0.0f; m[15] = 1.0f;
            params[b * 8 + 0] = c2;
            params[b * 8 + 1] = s2;
            params[b * 8 + 2] = c2 * xv - s2 * zv;
            params[b * 8 + 3] = yv;
            params[b * 8 + 4] = s2 * xv + c2 * zv;
            res[b][0] = -xv; res[b][1] = -yv; res[b][2] = -zv;
            res[b][3] = atan2f(s2, c2) * R2D;
        }
        __syncthreads();
    }

    if (tid == 0) {
        float tl2 = 0.0f, dl2 = 0.0f;
        for (int b = 0; b < NB; ++b) {
            const float* g = camg + b * 16;
            const float dx = res[b][0] - g[3];
            const float dy = res[b][1] - g[7];
            const float dz = res[b][2] - g[11];
            tl2 += dx * dx + dy * dy + dz * dz;
            const float dg = atan2f(g[2], g[10]) * R2D;
            const float dd = res[b][3] - dg;
            dl2 += dd * dd;
        }
        out[0] = tl2 * 0.25f + dl2 * 0.25f;
    }
}

// ---------------------------------------------------------------------------
// Kernel 3: warp feat1 by estimated transform -> feat1_warped (d_out + 65).
// ---------------------------------------------------------------------------
__global__ __launch_bounds__(256) void k_warp(const float* __restrict__ feat1,
                                              const float* __restrict__ params,
                                              float* __restrict__ outw)
{
    const int b = blockIdx.y;
    const int p = (int)blockIdx.x * 256 + (int)threadIdx.x;
    const int z = p >> 11;
    const int y = (p >> 6) & 31;
    const int x = p & 63;

    const float cs = params[b * 8 + 0], sn = params[b * 8 + 1];
    const float tpx = params[b * 8 + 2], tpy = params[b * 8 + 3], tpz = params[b * 8 + 4];

    const float rx = (float)x - 31.5f;
    const float ry = (float)y - 15.5f;
    const float rz = (float)z - 31.5f;
    const float sx = cs * rx - sn * rz + tpx + 31.5f;
    const float sy = ry + tpy + 15.5f;
    const float sz = sn * rx + cs * rz + tpz + 31.5f;

    const float xf = floorf(sx), yf = floorf(sy), zf = floorf(sz);
    const float fx = sx - xf, fy = sy - yf, fz = sz - zf;
    const int ix = (int)xf, iy = (int)yf, iz = (int)zf;

    const float wx[2] = {1.0f - fx, fx};
    const float wy[2] = {1.0f - fy, fy};
    const float wz[2] = {1.0f - fz, fz};
    const int xs[2] = {min(max(ix, 0), 63), min(max(ix + 1, 0), 63)};
    const int ys[2] = {min(max(iy, 0), 31), min(max(iy + 1, 0), 31)};
    const int zs[2] = {min(max(iz, 0), 63), min(max(iz + 1, 0), 63)};
    const bool vx[2] = {(unsigned)ix < 64u, (unsigned)(ix + 1) < 64u};
    const bool vy[2] = {(unsigned)iy < 32u, (unsigned)(iy + 1) < 32u};
    const bool vz[2] = {(unsigned)iz < 64u, (unsigned)(iz + 1) < 64u};

    int idx[8]; float w[8];
    int q = 0;
    #pragma unroll
    for (int dz = 0; dz < 2; ++dz)
        #pragma unroll
        for (int dy = 0; dy < 2; ++dy)
            #pragma unroll
            for (int dx = 0; dx < 2; ++dx) {
                idx[q] = zs[dz] * 2048 + ys[dy] * 64 + xs[dx];
                w[q] = (vx[dx] && vy[dy] && vz[dz]) ? wx[dx] * wy[dy] * wz[dz] : 0.0f;
                ++q;
            }

    const float* f1b = feat1 + (size_t)b * NCH * CHV;
    float* ob = outw + (size_t)b * NCH * CHV;
    #pragma unroll 1
    for (int c = 0; c < NCH; ++c) {
        const float* f1c = f1b + (size_t)c * CHV;
        float a = 0.0f;
        #pragma unroll
        for (int k = 0; k < 8; ++k) a += w[k] * f1c[idx[k]];
        ob[(size_t)c * CHV + p] = a;
    }
}

// ---------------------------------------------------------------------------
extern "C" void kernel_launch(void* const* d_in, const int* in_sizes, int n_in,
                              void* d_out, int out_size, void* d_ws, size_t ws_size,
                              hipStream_t stream)
{
    (void)in_sizes; (void)n_in; (void)out_size; (void)ws_size;
    const float* feat0 = (const float*)d_in[0];
    const float* feat1 = (const float*)d_in[1];
    const float* camg  = (const float*)d_in[2];
    const float* W1 = (const float*)d_in[3];
    const float* b1 = (const float*)d_in[4];
    const float* W2 = (const float*)d_in[5];
    const float* b2 = (const float*)d_in[6];
    const float* W3 = (const float*)d_in[7];
    const float* b3 = (const float*)d_in[8];
    float* out = (float*)d_out;

    float* partial = (float*)d_ws;                 // 324*512 floats ~ 663 KB
    float* params  = partial + 324 * NT2;          // 32 floats

    hipLaunchKernelGGL(k_heat, dim3(2048), dim3(256), 0, stream,
                       feat0, feat1, partial);
    hipLaunchKernelGGL(k_mlp, dim3(1), dim3(256), 0, stream,
                       partial, camg, W1, b1, W2, b2, W3, b3, out, params);
    dim3 g3((64*32*64) / 256, NB);
    hipLaunchKernelGGL(k_warp, g3, dim3(256), 0, stream, feat1, params, out + 65);
}

// Round 14
// 223.332 us; speedup vs baseline: 1.9446x; 1.0436x over previous
//
#include <hip/hip_runtime.h>
#include <math.h>

#define NCH 32
#define CHV (64*32*64)      // one channel volume
#define NB 4
#define NT2 512             // tile-slots per n: 32zt * 8yt * 2chh
#define INVC (1.0f/(32.0f+1e-6f))
#define D2R 0.017453292519943295f
#define R2D 57.29577951308232f

// feat1 LDS slab: 32 rows (8z x 4y) x pitch 72 (cols 0..63 data, 64..71 pad,
// never read). 72 mod 32 = 8 -> bilinear scalar reads ~2-way; rows 16B-aligned
// -> b128 stager writes conflict-free. OOB z rows staged as zeros.
#define P1 72
#define BUFSZ (32*P1)       // 2304 floats (9.2 KB); 4 buffers = 36.9 KB

// ---------------------------------------------------------------------------
// Kernel 1: fused rotate-warp(feat1) x 27-offset correlation vs feat0.
// Block = (b, chh, 2z x 4y x 64x tile): 256 threads.
// Waves 0/1/2 = rotations (-4 / 0 / +4 deg); wave 3 = dedicated feat1 stager.
// 2 channels per barrier phase (8 barriers instead of 16), 4 LDS buffers.
// Compute is software-pipelined inside each channel: rows for z-step k+1 are
// issued before FMA-ing z-step k, and the first rows are issued before the
// bilinear LDS work, so VMEM latency hides under VALU/LDS work.
// feat0 rows read direct from global (coalesced 1KB/wave, L1-shared by the
// 3 rotation waves, L2-resident via XCD-pinned block mapping).
// ---------------------------------------------------------------------------
__global__ __launch_bounds__(256) void k_heat(const float* __restrict__ feat0,
                                              const float* __restrict__ feat1,
                                              float* __restrict__ partial)
{
    __shared__ float L[4][BUFSZ];

    // XCD-chunked remap: XCD x gets 256 consecutive nids = exactly one (b,chh)
    const int lid = (int)blockIdx.x;            // 0..2047
    const int nid = (lid & 7) * 256 + (lid >> 3);
    const int yt  = nid & 7;
    const int zt  = (nid >> 3) & 31;
    const int chh = (nid >> 8) & 1;
    const int b   = nid >> 9;

    const int tid = (int)threadIdx.x;
    const int wv = tid >> 6;           // 0,1,2 compute rotations; 3 stager
    const int lane = tid & 63;
    const int tx = lane & 15, ty = lane >> 4;
    const int x0 = 4 * tx;
    const int y  = 4 * yt + ty;
    const int z0 = 2 * zt;             // thread owns z0, z0+1
    const bool yedge = (yt == 0) || (yt == 7);
    const bool ident = (wv == 1);
    const bool z0ok = (zt > 0);        // zri=0 feat0 row (z0-1) valid
    const bool z3ok = (zt < 31);       // zri=3 feat0 row (z0+2) valid

    const float* f0base = feat0 + ((size_t)b * NCH + chh * 16) * CHV;
    const float* f1base = feat1 + ((size_t)b * NCH + chh * 16) * CHV;

    // ---- bilinear setup (channel-invariant), rot waves 0/2 only ----
    int aB[2][4];
    float wAx[2][4], wBx[2][4], wZl[2][4];
    if (wv == 0 || wv == 2) {
        const float th = 4.0f * (float)(wv - 1) * D2R;
        const float cs = cosf(th), sn = sinf(th);
        #pragma unroll
        for (int k = 0; k < 2; ++k) {
            #pragma unroll
            for (int i = 0; i < 4; ++i) {
                const float rx = (float)(x0 + i) - 31.5f;
                const float rz = (float)(z0 + k) - 31.5f;
                const float sx = cs * rx - sn * rz + 31.5f;
                const float sz = sn * rx + cs * rz + 31.5f;
                const float xf = floorf(sx), zf = floorf(sz);
                const float fx = sx - xf, fz = sz - zf;
                const int ix = (int)xf, iz = (int)zf;
                int bx; float A_, B_;
                if (ix == -1)      { bx = 0;  A_ = fx;        B_ = 0.0f; }
                else if (ix == 63) { bx = 62; A_ = 0.0f;      B_ = 1.0f - fx; }
                else if ((unsigned)ix <= 62u) { bx = ix; A_ = 1.0f - fx; B_ = fx; }
                else               { bx = 0;  A_ = 0.0f;      B_ = 0.0f; }
                wAx[k][i] = A_; wBx[k][i] = B_;
                wZl[k][i] = 1.0f - fz;
                const int zl = min(max(iz - (2 * zt - 3), 0), 6);
                aB[k][i] = (zl * 4 + ty) * P1 + bx;
            }
        }
    }
    const int iA0 = (12 + ty) * P1 + x0;      // identity z0 row (zr=3)
    const int iA1 = iA0 + 4 * P1;             // identity z0+1 row (zr=4)

    // y-row masks + clamped offsets incl. x0 (channel-invariant, per lane)
    float myv[3]; int yoffc[3];
    #pragma unroll
    for (int yri = 0; yri < 3; ++yri) {
        const int yy = y - 1 + yri;
        myv[yri] = ((unsigned)yy < 32u) ? 1.0f : 0.0f;
        yoffc[yri] = min(max(yy, 0), 31) * 64 + x0;
    }

    float acc[27];
    #pragma unroll
    for (int o = 0; o < 27; ++o) acc[o] = 0.0f;

// ---- stager: stage a channel PAIR (16 loads in flight, then 16 writes) ----
#define STAGE2(CHN)                                                            \
    {                                                                           \
        const float* fA_ = f1base + (size_t)(CHN) * CHV;                        \
        const float* fB_ = fA_ + CHV;                                           \
        float* LA_ = &L[(CHN) & 3][0];                                          \
        float* LB_ = &L[((CHN) + 1) & 3][0];                                    \
        const int yr_ = lane >> 4, c4_ = (lane & 15) << 2;                      \
        const int wb_ = yr_ * P1 + c4_;                                         \
        const int sb_ = (4 * yt + yr_) * 64 + c4_;                              \
        float4 va_[8], vb_[8];                                                  \
        _Pragma("unroll")                                                       \
        for (int k_ = 0; k_ < 8; ++k_) {                                        \
            const int zs_ = 2 * zt - 3 + k_;                                    \
            va_[k_] = (float4){0.0f, 0.0f, 0.0f, 0.0f};                         \
            vb_[k_] = (float4){0.0f, 0.0f, 0.0f, 0.0f};                         \
            if (zs_ >= 0 && zs_ < 64) {                                         \
                va_[k_] = *(const float4*)(fA_ + zs_ * 2048 + sb_);             \
                vb_[k_] = *(const float4*)(fB_ + zs_ * 2048 + sb_);             \
            }                                                                   \
        }                                                                       \
        _Pragma("unroll")                                                       \
        for (int k_ = 0; k_ < 8; ++k_) {                                        \
            *(float4*)&LA_[k_ * (4 * P1) + wb_] = va_[k_];                      \
            *(float4*)&LB_[k_ * (4 * P1) + wb_] = vb_[k_];                      \
        }                                                                       \
    }

#define LOAD3(RB, ZRI)                                                          \
    { const int zc_ = min(max(2 * zt - 1 + (ZRI), 0), 63);                      \
      const float* rp_ = f0c + zc_ * 2048;                                      \
      RB[0] = *(const float4*)(rp_ + yoffc[0]);                                 \
      RB[1] = *(const float4*)(rp_ + yoffc[1]);                                 \
      RB[2] = *(const float4*)(rp_ + yoffc[2]); }

#define ROWFMA(KK, OZP1, YRI, R)                                                \
    { const int base_ = (OZP1) * 9 + (2 - (YRI)) * 3;                           \
      acc[base_ + 0] += g0[KK]*R.x + fr[KK][0]*R.y + fr[KK][1]*R.z + fr[KK][2]*R.w; \
      acc[base_ + 1] += fr[KK][0]*R.x + fr[KK][1]*R.y + fr[KK][2]*R.z + fr[KK][3]*R.w; \
      acc[base_ + 2] += fr[KK][1]*R.x + fr[KK][2]*R.y + fr[KK][3]*R.z + g5[KK]*R.w; }

#define FMASTEP(RB, ZRI, MASKED)                                                \
    { _Pragma("unroll")                                                         \
      for (int yri = 0; yri < 3; ++yri) {                                       \
        float4 R = RB[yri];                                                     \
        if (MASKED) { const float m_ = myv[yri];                                \
            R.x *= m_; R.y *= m_; R.z *= m_; R.w *= m_; }                       \
        if ((ZRI) == 0) { ROWFMA(0, 2, yri, R) }                                \
        if ((ZRI) == 1) { ROWFMA(0, 1, yri, R) ROWFMA(1, 2, yri, R) }           \
        if ((ZRI) == 2) { ROWFMA(0, 0, yri, R) ROWFMA(1, 1, yri, R) }           \
        if ((ZRI) == 3) { ROWFMA(1, 0, yri, R) }                                \
      } }

// Channel body: rows pipelined 1 z-step ahead; first rows issued before
// bilinear LDS work.
#define CHBODY(CH, MASKED)                                                      \
    {                                                                           \
        const float* f0c = f0base + (size_t)(CH) * CHV;                         \
        const float* Lb = &L[(CH) & 3][0];                                      \
        float4 Ra[3], Rb[3];                                                    \
        LOAD3(Ra, 0)                                                            \
        float fr[2][4];                                                         \
        if (ident) {                                                            \
            const float4 v0 = *(const float4*)&Lb[iA0];                         \
            const float4 v1 = *(const float4*)&Lb[iA1];                         \
            fr[0][0] = v0.x; fr[0][1] = v0.y; fr[0][2] = v0.z; fr[0][3] = v0.w; \
            fr[1][0] = v1.x; fr[1][1] = v1.y; fr[1][2] = v1.z; fr[1][3] = v1.w; \
        } else {                                                                \
            _Pragma("unroll")                                                   \
            for (int k = 0; k < 2; ++k) {                                       \
                _Pragma("unroll")                                               \
                for (int i = 0; i < 4; ++i) {                                   \
                    const int a = aB[k][i];                                     \
                    const float p00 = Lb[a], p01 = Lb[a + 1];                   \
                    const float p10 = Lb[a + 4 * P1], p11 = Lb[a + 4 * P1 + 1]; \
                    const float sLo = wAx[k][i] * p00 + wBx[k][i] * p01;        \
                    const float sHi = wAx[k][i] * p10 + wBx[k][i] * p11;        \
                    fr[k][i] = sHi + wZl[k][i] * (sLo - sHi);                   \
                }                                                               \
            }                                                                   \
        }                                                                       \
        float g0[2], g5[2];                                                     \
        _Pragma("unroll")                                                       \
        for (int k = 0; k < 2; ++k) {                                           \
            const float a_ = __shfl_up(fr[k][3], 1, 64);                        \
            const float c_ = __shfl_down(fr[k][0], 1, 64);                      \
            g0[k] = (tx == 0) ? 0.0f : a_;                                      \
            g5[k] = (tx == 15) ? 0.0f : c_;                                     \
        }                                                                       \
        LOAD3(Rb, 1)                                                            \
        if (z0ok) { FMASTEP(Ra, 0, MASKED) }                                    \
        LOAD3(Ra, 2)                                                            \
        FMASTEP(Rb, 1, MASKED)                                                  \
        LOAD3(Rb, 3)                                                            \
        FMASTEP(Ra, 2, MASKED)                                                  \
        if (z3ok) { FMASTEP(Rb, 3, MASKED) }                                    \
    }

    // ---- prologue: stager fills channels 0,1 into buffers 0,1 ----
    if (wv == 3) STAGE2(0)
    __syncthreads();

    #pragma unroll 1
    for (int p = 0; p < 8; ++p) {
        if (wv == 3) {
            if (p < 7) STAGE2(2 * p + 2)
        } else {
            __builtin_amdgcn_s_setprio(1);
            if (yedge) { CHBODY(2 * p, 1) CHBODY(2 * p + 1, 1) }
            else       { CHBODY(2 * p, 0) CHBODY(2 * p + 1, 0) }
            __builtin_amdgcn_s_setprio(0);
        }
        __syncthreads();
    }
#undef CHBODY
#undef FMASTEP
#undef ROWFMA
#undef LOAD3
#undef STAGE2

    // ---- per-wave reduction (fixed order -> deterministic), direct write ----
    if (wv < 3) {
        const int slot = (zt * 8 + yt) * 2 + chh;
        #pragma unroll 1
        for (int o = 0; o < 27; ++o) {
            float v = acc[o];
            #pragma unroll
            for (int d = 32; d >= 1; d >>= 1) v += __shfl_down(v, d, 64);
            if (lane == 0)
                partial[((size_t)((b * 3 + wv) * 27) + o) * NT2 + slot] = v;
        }
    }
}

// ---------------------------------------------------------------------------
// Kernel 2: reduce partials (transposed layout: [n*27][512] rows, vectorized)
// -> heat, per-batch MLP, loss + matrices + params.
// ---------------------------------------------------------------------------
__global__ __launch_bounds__(256) void k_mlp(const float* __restrict__ partial,
                                             const float* __restrict__ camg,
                                             const float* __restrict__ W1,
                                             const float* __restrict__ b1,
                                             const float* __restrict__ W2,
                                             const float* __restrict__ b2,
                                             const float* __restrict__ W3,
                                             const float* __restrict__ b3,
                                             float* __restrict__ out,
                                             float* __restrict__ params)
{
    __shared__ float heat[324];
    __shared__ float f[81];
    __shared__ float h1[128];
    __shared__ float h2[128];
    __shared__ float denom_s;
    __shared__ float res[NB][8];
    const int tid = (int)threadIdx.x;

    for (int r = tid; r < 324; r += 256) {
        const float4* p = (const float4*)(partial + (size_t)r * NT2);
        float s0 = 0.0f, s1 = 0.0f, s2 = 0.0f, s3 = 0.0f;
        #pragma unroll 4
        for (int i = 0; i < NT2 / 4; ++i) {
            const float4 v = p[i];
            s0 += v.x; s1 += v.y; s2 += v.z; s3 += v.w;
        }
        heat[r] = ((s0 + s1) + (s2 + s3)) * INVC;
    }
    __syncthreads();

    for (int b = 0; b < NB; ++b) {
        if (tid < 81) {
            float v = heat[b * 81 + tid];
            f[tid] = (v >= 0.0f) ? v : 0.1f * v;
        }
        __syncthreads();
        if (tid == 0) {
            float ss = 0.0f;
            for (int k = 0; k < 81; ++k) ss += f[k] * f[k];
            denom_s = 1e-6f + sqrtf(ss);
        }
        __syncthreads();
        if (tid < 81) f[tid] = f[tid] / denom_s;
        __syncthreads();
        if (tid < 128) {
            float a = b1[tid];
            const float* wr = W1 + tid * 81;
            for (int k = 0; k < 81; ++k) a += wr[k] * f[k];
            h1[tid] = (a >= 0.0f) ? a : 0.1f * a;
        }
        __syncthreads();
        if (tid < 128) {
            float a = b2[tid];
            const float* wr = W2 + tid * 128;
            for (int k = 0; k < 128; ++k) a += wr[k] * h1[k];
            h2[tid] = (a >= 0.0f) ? a : 0.1f * a;
        }
        __syncthreads();
        if (tid < 4) {
            float a = b3[tid];
            const float* wr = W3 + tid * 128;
            for (int k = 0; k < 128; ++k) a += wr[k] * h2[k];
            res[b][4 + tid] = a;
        }
        __syncthreads();
        if (tid == 0) {
            const float r_out = res[b][4], yv = res[b][5], xv = res[b][6], zv = res[b][7];
            const float t2 = r_out * D2R;
            const float c2 = cosf(t2), s2 = sinf(t2);
            float* m = out + 1 + b * 16;
            m[0] = c2;  m[1] = 0.0f; m[2] = s2;  m[3] = -xv;
            m[4] = 0.0f; m[5] = 1.0f; m[6] = 0.0f; m[7] = -yv;
            m[8] = -s2; m[9] = 0.0f; m[10] = c2; m[11] = -zv;
            m[12] = 0.0f; m[13] = 0.0f; m[14] = 0.0f; m[15] = 1.0f;
            params[b * 8 + 0] = c2;
            params[b * 8 + 1] = s2;
            params[b * 8 + 2] = c2 * xv - s2 * zv;
            params[b * 8 + 3] = yv;
            params[b * 8 + 4] = s2 * xv + c2 * zv;
            res[b][0] = -xv; res[b][1] = -yv; res[b][2] = -zv;
            res[b][3] = atan2f(s2, c2) * R2D;
        }
        __syncthreads();
    }

    if (tid == 0) {
        float tl2 = 0.0f, dl2 = 0.0f;
        for (int b = 0; b < NB; ++b) {
            const float* g = camg + b * 16;
            const float dx = res[b][0] - g[3];
            const float dy = res[b][1] - g[7];
            const float dz = res[b][2] - g[11];
            tl2 += dx * dx + dy * dy + dz * dz;
            const float dg = atan2f(g[2], g[10]) * R2D;
            const float dd = res[b][3] - dg;
            dl2 += dd * dd;
        }
        out[0] = tl2 * 0.25f + dl2 * 0.25f;
    }
}

// ---------------------------------------------------------------------------
// Kernel 3: warp feat1 by estimated transform -> feat1_warped (d_out + 65).
// ---------------------------------------------------------------------------
__global__ __launch_bounds__(256) void k_warp(const float* __restrict__ feat1,
                                              const float* __restrict__ params,
                                              float* __restrict__ outw)
{
    const int b = blockIdx.y;
    const int p = (int)blockIdx.x * 256 + (int)threadIdx.x;
    const int z = p >> 11;
    const int y = (p >> 6) & 31;
    const int x = p & 63;

    const float cs = params[b * 8 + 0], sn = params[b * 8 + 1];
    const float tpx = params[b * 8 + 2], tpy = params[b * 8 + 3], tpz = params[b * 8 + 4];

    const float rx = (float)x - 31.5f;
    const float ry = (float)y - 15.5f;
    const float rz = (float)z - 31.5f;
    const float sx = cs * rx - sn * rz + tpx + 31.5f;
    const float sy = ry + tpy + 15.5f;
    const float sz = sn * rx + cs * rz + tpz + 31.5f;

    const float xf = floorf(sx), yf = floorf(sy), zf = floorf(sz);
    const float fx = sx - xf, fy = sy - yf, fz = sz - zf;
    const int ix = (int)xf, iy = (int)yf, iz = (int)zf;

    const float wx[2] = {1.0f - fx, fx};
    const float wy[2] = {1.0f - fy, fy};
    const float wz[2] = {1.0f - fz, fz};
    const int xs[2] = {min(max(ix, 0), 63), min(max(ix + 1, 0), 63)};
    const int ys[2] = {min(max(iy, 0), 31), min(max(iy + 1, 0), 31)};
    const int zs[2] = {min(max(iz, 0), 63), min(max(iz + 1, 0), 63)};
    const bool vx[2] = {(unsigned)ix < 64u, (unsigned)(ix + 1) < 64u};
    const bool vy[2] = {(unsigned)iy < 32u, (unsigned)(iy + 1) < 32u};
    const bool vz[2] = {(unsigned)iz < 64u, (unsigned)(iz + 1) < 64u};

    int idx[8]; float w[8];
    int q = 0;
    #pragma unroll
    for (int dz = 0; dz < 2; ++dz)
        #pragma unroll
        for (int dy = 0; dy < 2; ++dy)
            #pragma unroll
            for (int dx = 0; dx < 2; ++dx) {
                idx[q] = zs[dz] * 2048 + ys[dy] * 64 + xs[dx];
                w[q] = (vx[dx] && vy[dy] && vz[dz]) ? wx[dx] * wy[dy] * wz[dz] : 0.0f;
                ++q;
            }

    const float* f1b = feat1 + (size_t)b * NCH * CHV;
    float* ob = outw + (size_t)b * NCH * CHV;
    #pragma unroll 1
    for (int c = 0; c < NCH; ++c) {
        const float* f1c = f1b + (size_t)c * CHV;
        float a = 0.0f;
        #pragma unroll
        for (int k = 0; k < 8; ++k) a += w[k] * f1c[idx[k]];
        ob[(size_t)c * CHV + p] = a;
    }
}

// ---------------------------------------------------------------------------
extern "C" void kernel_launch(void* const* d_in, const int* in_sizes, int n_in,
                              void* d_out, int out_size, void* d_ws, size_t ws_size,
                              hipStream_t stream)
{
    (void)in_sizes; (void)n_in; (void)out_size; (void)ws_size;
    const float* feat0 = (const float*)d_in[0];
    const float* feat1 = (const float*)d_in[1];
    const float* camg  = (const float*)d_in[2];
    const float* W1 = (const float*)d_in[3];
    const float* b1 = (const float*)d_in[4];
    const float* W2 = (const float*)d_in[5];
    const float* b2 = (const float*)d_in[6];
    const float* W3 = (const float*)d_in[7];
    const float* b3 = (const float*)d_in[8];
    float* out = (float*)d_out;

    float* partial = (float*)d_ws;                 // 324*512 floats ~ 663 KB
    float* params  = partial + 324 * NT2;          // 32 floats

    hipLaunchKernelGGL(k_heat, dim3(2048), dim3(256), 0, stream,
                       feat0, feat1, partial);
    hipLaunchKernelGGL(k_mlp, dim3(1), dim3(256), 0, stream,
                       partial, camg, W1, b1, W2, b2, W3, b3, out, params);
    dim3 g3((64*32*64) / 256, NB);
    hipLaunchKernelGGL(k_warp, g3, dim3(256), 0, stream, feat1, params, out + 65);
}

// Round 15
// 213.153 us; speedup vs baseline: 2.0375x; 1.0478x over previous
//
#include <hip/hip_runtime.h>
#include <math.h>

#define NCH 32
#define CHV (64*32*64)      // one channel volume
#define NB 4
#define NT2 512             // tile-slots per n: 32zt * 8yt * 2chh
#define INVC (1.0f/(32.0f+1e-6f))
#define D2R 0.017453292519943295f
#define R2D 57.29577951308232f

// LDS unit (one channel): feat1 slab 32 rows (8z x 4y) x pitch 72 at [0],
// feat0 slab 24 rows (4z x 6y) x pitch 72 at [F0B]. Pitch 72: b128 rows are
// 16B-aligned & conflict-free (4tx+8ty covers all banks evenly); scalar
// bilinear reads ~2-way. OOB z/y rows staged as ZEROS -> no masking anywhere.
#define P1 72
#define F0B (32*P1)         // 2304
#define UNITSZ (32*P1 + 24*P1)   // 4032 floats (16.1 KB); 2 units = 32.3 KB

// ---------------------------------------------------------------------------
// Kernel 1: fused rotate-warp(feat1) x 27-offset correlation vs feat0.
// Block = (b, chh, 2z x 4y x 64x tile): 256 threads.
// Waves 0/1/2 = rotations (-4 / 0 / +4 deg); wave 3 = dedicated stager that
// stages BOTH feat1 (8 z-rows) and feat0 (4z x 6y tile) per channel, with
// OOB rows zeroed. Double-buffered, 1 barrier/channel. Compute waves touch
// ONLY LDS: correlation rows are ds_read_b128 at compile-time immediate
// offsets (zero address VALU), no edge masks, one uniform code path.
// ---------------------------------------------------------------------------
__global__ __launch_bounds__(256) void k_heat(const float* __restrict__ feat0,
                                              const float* __restrict__ feat1,
                                              float* __restrict__ partial)
{
    __shared__ float L[2][UNITSZ];

    // XCD-chunked remap: XCD x gets 256 consecutive nids = exactly one (b,chh)
    const int lid = (int)blockIdx.x;            // 0..2047
    const int nid = (lid & 7) * 256 + (lid >> 3);
    const int yt  = nid & 7;
    const int zt  = (nid >> 3) & 31;
    const int chh = (nid >> 8) & 1;
    const int b   = nid >> 9;

    const int tid = (int)threadIdx.x;
    const int wv = tid >> 6;           // 0,1,2 compute rotations; 3 stager
    const int lane = tid & 63;
    const int tx = lane & 15, ty = lane >> 4;
    const int x0 = 4 * tx;
    const int z0 = 2 * zt;             // thread owns z0, z0+1
    const bool ident = (wv == 1);

    const float* f0base = feat0 + ((size_t)b * NCH + chh * 16) * CHV;
    const float* f1base = feat1 + ((size_t)b * NCH + chh * 16) * CHV;

    // ---- bilinear setup (channel-invariant), rot waves 0/2 only ----
    int aB[2][4];
    float wAx[2][4], wBx[2][4], wZl[2][4];
    if (wv == 0 || wv == 2) {
        const float th = 4.0f * (float)(wv - 1) * D2R;
        const float cs = cosf(th), sn = sinf(th);
        #pragma unroll
        for (int k = 0; k < 2; ++k) {
            #pragma unroll
            for (int i = 0; i < 4; ++i) {
                const float rx = (float)(x0 + i) - 31.5f;
                const float rz = (float)(z0 + k) - 31.5f;
                const float sx = cs * rx - sn * rz + 31.5f;
                const float sz = sn * rx + cs * rz + 31.5f;
                const float xf = floorf(sx), zf = floorf(sz);
                const float fx = sx - xf, fz = sz - zf;
                const int ix = (int)xf, iz = (int)zf;
                int bx; float A_, B_;
                if (ix == -1)      { bx = 0;  A_ = fx;        B_ = 0.0f; }
                else if (ix == 63) { bx = 62; A_ = 0.0f;      B_ = 1.0f - fx; }
                else if ((unsigned)ix <= 62u) { bx = ix; A_ = 1.0f - fx; B_ = fx; }
                else               { bx = 0;  A_ = 0.0f;      B_ = 0.0f; }
                wAx[k][i] = A_; wBx[k][i] = B_;
                wZl[k][i] = 1.0f - fz;
                const int zl = min(max(iz - (2 * zt - 3), 0), 6);
                aB[k][i] = (zl * 4 + ty) * P1 + bx;
            }
        }
    }
    const int iA0 = (12 + ty) * P1 + x0;      // identity z0 row (zr=3)
    const int iA1 = iA0 + 4 * P1;             // identity z0+1 row (zr=4)
    const int fb0 = F0B + ty * P1 + x0;       // feat0 corr base (row j=ty)

    float acc[27];
    #pragma unroll
    for (int o = 0; o < 27; ++o) acc[o] = 0.0f;

// ---- stager: feat1 (8 rows/lane-group) + feat0 (6 rows/lane-group) ----
// feat1 LDS row (zr*4+yr) <- global z = 2zt-3+zr, y = 4yt+yr (z-OOB -> 0).
// feat0 LDS row r=i*6+j  <- global z = 2zt-1+i, y = 4yt-1+j (z/y-OOB -> 0).
#define STAGE_CH(CHN)                                                           \
    {                                                                           \
        const int u_ = (CHN) & 1;                                               \
        const float* f1c_ = f1base + (size_t)(CHN) * CHV;                       \
        const float* f0c_ = f0base + (size_t)(CHN) * CHV;                       \
        float* Ln_ = &L[u_][0];                                                 \
        const int tq_ = lane >> 4, c4_ = (lane & 15) << 2;                      \
        float4 v1_[8], v0_[6];                                                  \
        _Pragma("unroll")                                                       \
        for (int k_ = 0; k_ < 8; ++k_) {                                        \
            const int zs_ = 2 * zt - 3 + k_;                                    \
            v1_[k_] = (float4){0.0f, 0.0f, 0.0f, 0.0f};                         \
            if (zs_ >= 0 && zs_ < 64)                                           \
                v1_[k_] = *(const float4*)(f1c_ + zs_ * 2048                    \
                            + (4 * yt + tq_) * 64 + c4_);                       \
        }                                                                       \
        _Pragma("unroll")                                                       \
        for (int k_ = 0; k_ < 6; ++k_) {                                        \
            const int r_ = 4 * k_ + tq_;                                        \
            const int i_ = (r_ * 43) >> 8;                                      \
            const int j_ = r_ - 6 * i_;                                         \
            const int zf_ = 2 * zt - 1 + i_;                                    \
            const int yf_ = 4 * yt - 1 + j_;                                    \
            v0_[k_] = (float4){0.0f, 0.0f, 0.0f, 0.0f};                         \
            if (zf_ >= 0 && zf_ < 64 && yf_ >= 0 && yf_ < 32)                   \
                v0_[k_] = *(const float4*)(f0c_ + zf_ * 2048 + yf_ * 64 + c4_); \
        }                                                                       \
        _Pragma("unroll")                                                       \
        for (int k_ = 0; k_ < 8; ++k_)                                          \
            *(float4*)&Ln_[(4 * k_ + tq_) * P1 + c4_] = v1_[k_];                \
        _Pragma("unroll")                                                       \
        for (int k_ = 0; k_ < 6; ++k_)                                          \
            *(float4*)&Ln_[F0B + (4 * k_ + tq_) * P1 + c4_] = v0_[k_];          \
    }

#define ROWFMA(KK, OZP1, YRI, R)                                                \
    { const int base_ = (OZP1) * 9 + (2 - (YRI)) * 3;                           \
      acc[base_ + 0] += g0[KK]*R.x + fr[KK][0]*R.y + fr[KK][1]*R.z + fr[KK][2]*R.w; \
      acc[base_ + 1] += fr[KK][0]*R.x + fr[KK][1]*R.y + fr[KK][2]*R.z + fr[KK][3]*R.w; \
      acc[base_ + 2] += fr[KK][1]*R.x + fr[KK][2]*R.y + fr[KK][3]*R.z + g5[KK]*R.w; }

    // prologue: stager fills channel 0 into unit 0
    if (wv == 3) STAGE_CH(0)
    __syncthreads();

    #pragma unroll 1
    for (int ch = 0; ch < 16; ++ch) {
        if (wv == 3) {
            if (ch + 1 < 16) STAGE_CH(ch + 1)
        } else {
            const float* Lb = &L[ch & 1][0];

            // ---- featN sample: fr[k][i] (LDS only) ----
            float fr[2][4];
            if (ident) {
                const float4 v0 = *(const float4*)&Lb[iA0];
                const float4 v1 = *(const float4*)&Lb[iA1];
                fr[0][0] = v0.x; fr[0][1] = v0.y; fr[0][2] = v0.z; fr[0][3] = v0.w;
                fr[1][0] = v1.x; fr[1][1] = v1.y; fr[1][2] = v1.z; fr[1][3] = v1.w;
            } else {
                #pragma unroll
                for (int k = 0; k < 2; ++k) {
                    #pragma unroll
                    for (int i = 0; i < 4; ++i) {
                        const int a = aB[k][i];
                        const float p00 = Lb[a], p01 = Lb[a + 1];
                        const float p10 = Lb[a + 4 * P1], p11 = Lb[a + 4 * P1 + 1];
                        const float sLo = wAx[k][i] * p00 + wBx[k][i] * p01;
                        const float sHi = wAx[k][i] * p10 + wBx[k][i] * p11;
                        fr[k][i] = sHi + wZl[k][i] * (sLo - sHi);
                    }
                }
            }

            // ---- featN x-extension (4 shuffles/ch) ----
            float g0[2], g5[2];
            #pragma unroll
            for (int k = 0; k < 2; ++k) {
                const float a_ = __shfl_up(fr[k][3], 1, 64);
                const float c_ = __shfl_down(fr[k][0], 1, 64);
                g0[k] = (tx == 0) ? 0.0f : a_;
                g5[k] = (tx == 15) ? 0.0f : c_;
            }

            // ---- correlation: 12 feat0 rows from LDS, imm offsets, no masks ----
            __builtin_amdgcn_s_setprio(1);
            #pragma unroll
            for (int zri = 0; zri < 4; ++zri) {
                const float4 R0 = *(const float4*)&Lb[fb0 + (zri * 6 + 0) * P1];
                const float4 R1 = *(const float4*)&Lb[fb0 + (zri * 6 + 1) * P1];
                const float4 R2 = *(const float4*)&Lb[fb0 + (zri * 6 + 2) * P1];
                if (zri == 0) { ROWFMA(0, 2, 0, R0) ROWFMA(0, 2, 1, R1) ROWFMA(0, 2, 2, R2) }
                if (zri == 1) { ROWFMA(0, 1, 0, R0) ROWFMA(0, 1, 1, R1) ROWFMA(0, 1, 2, R2)
                                ROWFMA(1, 2, 0, R0) ROWFMA(1, 2, 1, R1) ROWFMA(1, 2, 2, R2) }
                if (zri == 2) { ROWFMA(0, 0, 0, R0) ROWFMA(0, 0, 1, R1) ROWFMA(0, 0, 2, R2)
                                ROWFMA(1, 1, 0, R0) ROWFMA(1, 1, 1, R1) ROWFMA(1, 1, 2, R2) }
                if (zri == 3) { ROWFMA(1, 0, 0, R0) ROWFMA(1, 0, 1, R1) ROWFMA(1, 0, 2, R2) }
            }
            __builtin_amdgcn_s_setprio(0);
        }
        __syncthreads();
    }
#undef ROWFMA
#undef STAGE_CH

    // ---- per-wave reduction (fixed order -> deterministic), direct write ----
    if (wv < 3) {
        const int slot = (zt * 8 + yt) * 2 + chh;
        #pragma unroll 1
        for (int o = 0; o < 27; ++o) {
            float v = acc[o];
            #pragma unroll
            for (int d = 32; d >= 1; d >>= 1) v += __shfl_down(v, d, 64);
            if (lane == 0)
                partial[((size_t)((b * 3 + wv) * 27) + o) * NT2 + slot] = v;
        }
    }
}

// ---------------------------------------------------------------------------
// Kernel 2: reduce partials (transposed layout: [n*27][512] rows, vectorized)
// -> heat, per-batch MLP, loss + matrices + params.
// ---------------------------------------------------------------------------
__global__ __launch_bounds__(256) void k_mlp(const float* __restrict__ partial,
                                             const float* __restrict__ camg,
                                             const float* __restrict__ W1,
                                             const float* __restrict__ b1,
                                             const float* __restrict__ W2,
                                             const float* __restrict__ b2,
                                             const float* __restrict__ W3,
                                             const float* __restrict__ b3,
                                             float* __restrict__ out,
                                             float* __restrict__ params)
{
    __shared__ float heat[324];
    __shared__ float f[81];
    __shared__ float h1[128];
    __shared__ float h2[128];
    __shared__ float denom_s;
    __shared__ float res[NB][8];
    const int tid = (int)threadIdx.x;

    for (int r = tid; r < 324; r += 256) {
        const float4* p = (const float4*)(partial + (size_t)r * NT2);
        float s0 = 0.0f, s1 = 0.0f, s2 = 0.0f, s3 = 0.0f;
        #pragma unroll 4
        for (int i = 0; i < NT2 / 4; ++i) {
            const float4 v = p[i];
            s0 += v.x; s1 += v.y; s2 += v.z; s3 += v.w;
        }
        heat[r] = ((s0 + s1) + (s2 + s3)) * INVC;
    }
    __syncthreads();

    for (int b = 0; b < NB; ++b) {
        if (tid < 81) {
            float v = heat[b * 81 + tid];
            f[tid] = (v >= 0.0f) ? v : 0.1f * v;
        }
        __syncthreads();
        if (tid == 0) {
            float ss = 0.0f;
            for (int k = 0; k < 81; ++k) ss += f[k] * f[k];
            denom_s = 1e-6f + sqrtf(ss);
        }
        __syncthreads();
        if (tid < 81) f[tid] = f[tid] / denom_s;
        __syncthreads();
        if (tid < 128) {
            float a = b1[tid];
            const float* wr = W1 + tid * 81;
            for (int k = 0; k < 81; ++k) a += wr[k] * f[k];
            h1[tid] = (a >= 0.0f) ? a : 0.1f * a;
        }
        __syncthreads();
        if (tid < 128) {
            float a = b2[tid];
            const float* wr = W2 + tid * 128;
            for (int k = 0; k < 128; ++k) a += wr[k] * h1[k];
            h2[tid] = (a >= 0.0f) ? a : 0.1f * a;
        }
        __syncthreads();
        if (tid < 4) {
            float a = b3[tid];
            const float* wr = W3 + tid * 128;
            for (int k = 0; k < 128; ++k) a += wr[k] * h2[k];
            res[b][4 + tid] = a;
        }
        __syncthreads();
        if (tid == 0) {
            const float r_out = res[b][4], yv = res[b][5], xv = res[b][6], zv = res[b][7];
            const float t2 = r_out * D2R;
            const float c2 = cosf(t2), s2 = sinf(t2);
            float* m = out + 1 + b * 16;
            m[0] = c2;  m[1] = 0.0f; m[2] = s2;  m[3] = -xv;
            m[4] = 0.0f; m[5] = 1.0f; m[6] = 0.0f; m[7] = -yv;
            m[8] = -s2; m[9] = 0.0f; m[10] = c2; m[11] = -zv;
            m[12] = 0.0f; m[13] = 0.0f; m[14] = 0.0f; m[15] = 1.0f;
            params[b * 8 + 0] = c2;
            params[b * 8 + 1] = s2;
            params[b * 8 + 2] = c2 * xv - s2 * zv;
            params[b * 8 + 3] = yv;
            params[b * 8 + 4] = s2 * xv + c2 * zv;
            res[b][0] = -xv; res[b][1] = -yv; res[b][2] = -zv;
            res[b][3] = atan2f(s2, c2) * R2D;
        }
        __syncthreads();
    }

    if (tid == 0) {
        float tl2 = 0.0f, dl2 = 0.0f;
        for (int b = 0; b < NB; ++b) {
            const float* g = camg + b * 16;
            const float dx = res[b][0] - g[3];
            const float dy = res[b][1] - g[7];
            const float dz = res[b][2] - g[11];
            tl2 += dx * dx + dy * dy + dz * dz;
            const float dg = atan2f(g[2], g[10]) * R2D;
            const float dd = res[b][3] - dg;
            dl2 += dd * dd;
        }
        out[0] = tl2 * 0.25f + dl2 * 0.25f;
    }
}

// ---------------------------------------------------------------------------
// Kernel 3: warp feat1 by estimated transform -> feat1_warped (d_out + 65).
// ---------------------------------------------------------------------------
__global__ __launch_bounds__(256) void k_warp(const float* __restrict__ feat1,
                                              const float* __restrict__ params,
                                              float* __restrict__ outw)
{
    const int b = blockIdx.y;
    const int p = (int)blockIdx.x * 256 + (int)threadIdx.x;
    const int z = p >> 11;
    const int y = (p >> 6) & 31;
    const int x = p & 63;

    const float cs = params[b * 8 + 0], sn = params[b * 8 + 1];
    const float tpx = params[b * 8 + 2], tpy = params[b * 8 + 3], tpz = params[b * 8 + 4];

    const float rx = (float)x - 31.5f;
    const float ry = (float)y - 15.5f;
    const float rz = (float)z - 31.5f;
    const float sx = cs * rx - sn * rz + tpx + 31.5f;
    const float sy = ry + tpy + 15.5f;
    const float sz = sn * rx + cs * rz + tpz + 31.5f;

    const float xf = floorf(sx), yf = floorf(sy), zf = floorf(sz);
    const float fx = sx - xf, fy = sy - yf, fz = sz - zf;
    const int ix = (int)xf, iy = (int)yf, iz = (int)zf;

    const float wx[2] = {1.0f - fx, fx};
    const float wy[2] = {1.0f - fy, fy};
    const float wz[2] = {1.0f - fz, fz};
    const int xs[2] = {min(max(ix, 0), 63), min(max(ix + 1, 0), 63)};
    const int ys[2] = {min(max(iy, 0), 31), min(max(iy + 1, 0), 31)};
    const int zs[2] = {min(max(iz, 0), 63), min(max(iz + 1, 0), 63)};
    const bool vx[2] = {(unsigned)ix < 64u, (unsigned)(ix + 1) < 64u};
    const bool vy[2] = {(unsigned)iy < 32u, (unsigned)(iy + 1) < 32u};
    const bool vz[2] = {(unsigned)iz < 64u, (unsigned)(iz + 1) < 64u};

    int idx[8]; float w[8];
    int q = 0;
    #pragma unroll
    for (int dz = 0; dz < 2; ++dz)
        #pragma unroll
        for (int dy = 0; dy < 2; ++dy)
            #pragma unroll
            for (int dx = 0; dx < 2; ++dx) {
                idx[q] = zs[dz] * 2048 + ys[dy] * 64 + xs[dx];
                w[q] = (vx[dx] && vy[dy] && vz[dz]) ? wx[dx] * wy[dy] * wz[dz] : 0.0f;
                ++q;
            }

    const float* f1b = feat1 + (size_t)b * NCH * CHV;
    float* ob = outw + (size_t)b * NCH * CHV;
    #pragma unroll 1
    for (int c = 0; c < NCH; ++c) {
        const float* f1c = f1b + (size_t)c * CHV;
        float a = 0.0f;
        #pragma unroll
        for (int k = 0; k < 8; ++k) a += w[k] * f1c[idx[k]];
        ob[(size_t)c * CHV + p] = a;
    }
}

// ---------------------------------------------------------------------------
extern "C" void kernel_launch(void* const* d_in, const int* in_sizes, int n_in,
                              void* d_out, int out_size, void* d_ws, size_t ws_size,
                              hipStream_t stream)
{
    (void)in_sizes; (void)n_in; (void)out_size; (void)ws_size;
    const float* feat0 = (const float*)d_in[0];
    const float* feat1 = (const float*)d_in[1];
    const float* camg  = (const float*)d_in[2];
    const float* W1 = (const float*)d_in[3];
    const float* b1 = (const float*)d_in[4];
    const float* W2 = (const float*)d_in[5];
    const float* b2 = (const float*)d_in[6];
    const float* W3 = (const float*)d_in[7];
    const float* b3 = (const float*)d_in[8];
    float* out = (float*)d_out;

    float* partial = (float*)d_ws;                 // 324*512 floats ~ 663 KB
    float* params  = partial + 324 * NT2;          // 32 floats

    hipLaunchKernelGGL(k_heat, dim3(2048), dim3(256), 0, stream,
                       feat0, feat1, partial);
    hipLaunchKernelGGL(k_mlp, dim3(1), dim3(256), 0, stream,
                       partial, camg, W1, b1, W2, b2, W3, b3, out, params);
    dim3 g3((64*32*64) / 256, NB);
    hipLaunchKernelGGL(k_warp, g3, dim3(256), 0, stream, feat1, params, out + 65);
}